// Round 5
// baseline (518.008 us; speedup 1.0000x reference)
//
#include <hip/hip_runtime.h>
#include <stdint.h>
#include <stddef.h>

typedef __bf16 bft;
typedef __bf16 bf16x4 __attribute__((ext_vector_type(4)));
typedef __bf16 bf16x8 __attribute__((ext_vector_type(8)));
typedef float f32x4 __attribute__((ext_vector_type(4)));

#define NH 12
#define HD 64
#define SEQ 1025
#define NB 32
#define DMODEL 768
#define MROWS (NB * SEQ)   /* 32800 */
#define BHN (NB * NH)      /* 384 */
#define BSTR 1040          /* padded per-batch token stride for QKV GEMM M dim */
#define MP (NB * BSTR)     /* 33280 padded M */
#define SEQP 1056          /* kfT/vT column stride (33 chunks of 32) */

__device__ __forceinline__ void gl_lds16(const void* g, void* l) {
  __builtin_amdgcn_global_load_lds(
      (const __attribute__((address_space(1))) void*)g,
      (__attribute__((address_space(3))) void*)l, 16, 0, 0);
}

__device__ __forceinline__ bf16x4 ds_tr16(const bft* p, int boff) {
  bf16x4 d;
  asm volatile("ds_read_b64_tr_b16 %0, %1 offset:%2"
               : "=v"(d)
               : "v"((const __attribute__((address_space(3))) bft*)p), "i"(boff)
               : "memory");
  return d;
}

__device__ __forceinline__ void lgkm0() {
  asm volatile("s_waitcnt lgkmcnt(0)" ::: "memory");
}

// ---------------- K0: fused prep (casts + padzero + rope tables) ----------------
#define S0P 6297600              /* x cast, f32x4 units */
#define S1P (S0P + 442368)       /* wqkv */
#define S2P (S1P + 147456)       /* wout */
#define S3P (S2P + 1024)         /* proj */
#define S4P (S3P + 24576)        /* padzero rows */
#define S5P (S4P + 33280)        /* rope items 1040*32 */

__global__ __launch_bounds__(256) void k_prep(
    const float* __restrict__ X, const float* __restrict__ WQKV,
    const float* __restrict__ WOUT, const float* __restrict__ PROJ,
    const float* __restrict__ FC, const float* __restrict__ FS,
    bft* __restrict__ XB, bft* __restrict__ WQKVB, bft* __restrict__ WOUTB,
    bft* __restrict__ PROJB, bft* __restrict__ KFT, bft* __restrict__ VT,
    float* __restrict__ FCP, float* __restrict__ FSP) {
  const int i = blockIdx.x * 256 + threadIdx.x;
  if (i < S0P) {
    f32x4 v = *(const f32x4*)(X + (size_t)i * 4);
    bf16x4 o; o[0]=(bft)v[0]; o[1]=(bft)v[1]; o[2]=(bft)v[2]; o[3]=(bft)v[3];
    *(bf16x4*)(XB + (size_t)i * 4) = o;
  } else if (i < S1P) {
    int k = i - S0P;
    f32x4 v = *(const f32x4*)(WQKV + (size_t)k * 4);
    bf16x4 o; o[0]=(bft)v[0]; o[1]=(bft)v[1]; o[2]=(bft)v[2]; o[3]=(bft)v[3];
    *(bf16x4*)(WQKVB + (size_t)k * 4) = o;
  } else if (i < S2P) {
    int k = i - S1P;
    f32x4 v = *(const f32x4*)(WOUT + (size_t)k * 4);
    bf16x4 o; o[0]=(bft)v[0]; o[1]=(bft)v[1]; o[2]=(bft)v[2]; o[3]=(bft)v[3];
    *(bf16x4*)(WOUTB + (size_t)k * 4) = o;
  } else if (i < S3P) {
    int k = i - S2P;
    f32x4 v = *(const f32x4*)(PROJ + (size_t)k * 4);
    bf16x4 o; o[0]=(bft)v[0]; o[1]=(bft)v[1]; o[2]=(bft)v[2]; o[3]=(bft)v[3];
    *(bf16x4*)(PROJB + (size_t)k * 4) = o;
  } else if (i < S4P) {
    int r = i - S3P;
    bft* a = KFT + (size_t)r * SEQP + 1025;
    bft* b = VT + (size_t)r * SEQP + 1025;
#pragma unroll
    for (int q = 0; q < 31; ++q) { a[q] = (bft)0.f; b[q] = (bft)0.f; }
  } else if (i < S5P) {
    int k = i - S4P;
    int n = k >> 5;
    int fj = k & 31;
    float c = 1.f, s = 0.f;
    if (n >= 1 && n <= 1024) {
      c = FC[(n - 1) * 32 + fj];
      s = FS[(n - 1) * 32 + fj];
    }
    FCP[k] = c;
    FSP[k] = s;
  }
}

// ---------------- K1: QKV GEMM + fused RoPE + feature map ----------------
// 1D grid 4680 = 8 XCD chunks x 585, column-fastest logical order.
__global__ __launch_bounds__(256) void k_qkv_gemm(
    const bft* __restrict__ X, const bft* __restrict__ W,
    const bft* __restrict__ P,
    const float* __restrict__ FCP, const float* __restrict__ FSP,
    bft* __restrict__ QF, bft* __restrict__ KFT, bft* __restrict__ VT) {
  __shared__ __align__(16) bft sAll[128 * 64 * 2];  // 32 KB: [0,8192)=A, [8192,16384)=B
  bft* sA = sAll;
  bft* sB = sAll + 8192;
  const int tid = threadIdx.x;
  const int lane = tid & 63;
  const int lm = lane & 15;
  const int quad = lane >> 4;
  const int wid = tid >> 6;
  const int wm = (wid & 1) << 6;
  const int wn = (wid >> 1) << 6;
  const int lin = blockIdx.x;
  const int logical = (lin & 7) * 585 + (lin >> 3);
  const int cb = logical % 18;
  const int rb = logical / 18;
  const int m0 = rb * 128;
  const int n0 = cb * 128;
  const int sw = lm & 7;
  const int o0 = (quad ^ sw) << 3;
  const int o1 = ((4 + quad) ^ sw) << 3;

  // hoist K-invariant staging addresses
  const bft* aptr[4];
  const bft* bptr[4];
#pragma unroll
  for (int it = 0; it < 4; it++) {
    int c = it * 256 + tid;
    int row = c >> 3;
    int col = ((c & 7) ^ (row & 7)) << 3;
    int ar = m0 + row;
    int b2 = ar / BSTR;
    int nn = ar - b2 * BSTR;
    if (nn > 1024) nn = 1024;
    aptr[it] = X + (size_t)(b2 * SEQ + nn) * DMODEL + col;
    bptr[it] = W + (size_t)(n0 + row) * DMODEL + col;
  }

  f32x4 acc[4][4] = {};

  for (int kt = 0; kt < DMODEL; kt += 64) {
#pragma unroll
    for (int it = 0; it < 4; it++) {
      int c = it * 256 + tid;
      gl_lds16(aptr[it], sA + c * 8);
      gl_lds16(bptr[it], sB + c * 8);
      aptr[it] += 64;
      bptr[it] += 64;
    }
    __syncthreads();
#pragma unroll
    for (int kk = 0; kk < 2; kk++) {
      const int off = kk ? o1 : o0;
      bf16x8 af[4], bb[4];
#pragma unroll
      for (int i = 0; i < 4; i++)
        af[i] = *(const bf16x8*)(sA + (wm + i * 16 + lm) * 64 + off);
#pragma unroll
      for (int j = 0; j < 4; j++)
        bb[j] = *(const bf16x8*)(sB + (wn + j * 16 + lm) * 64 + off);
#pragma unroll
      for (int i = 0; i < 4; i++)
#pragma unroll
        for (int j = 0; j < 4; j++)
          acc[i][j] = __builtin_amdgcn_mfma_f32_16x16x32_bf16(af[i], bb[j], acc[i][j], 0, 0, 0);
    }
    __syncthreads();
  }

  const int s = cb / 6;
  const int h = ((n0 + wn) - s * DMODEL) >> 6;

  // per-wave transpose scratch: 4 tiles of [64 d][16 tok] bf16, 8 KB/wave
  bft* tt = sAll + wid * 4096;
  const bft* tl = tt + quad * 128 + lm * 4;

  if (s < 2) {
    const float sgn = (lm & 1) ? 1.f : -1.f;
    int bb2s[4], nbs[4];
    // Phase 1: RoPE all 4 i-tiles, write to tt_i (vector b64)
#pragma unroll
    for (int i = 0; i < 4; i++) {
      const int tbase = m0 + wm + i * 16;
      bb2s[i] = tbase / BSTR;
      nbs[i] = tbase - bb2s[i] * BSTR;
#pragma unroll
      for (int j = 0; j < 4; j++) {
        const int d = j * 16 + lm;
        const int fj = d >> 1;
        bf16x4 w;
#pragma unroll
        for (int r = 0; r < 4; r++) {
          float v = acc[i][j][r];
          float pv = __shfl_xor(v, 1);
          int n = nbs[i] + quad * 4 + r;
          float cc = FCP[n * 32 + fj];
          float ss = FSP[n * 32 + fj];
          w[r] = (bft)fmaf(pv, sgn * ss, v * cc);
        }
        *(bf16x4*)(tt + i * 1024 + d * 16 + quad * 4) = w;
      }
    }
    lgkm0();
    // Phase 2: all 16 tr-reads, single wait
    bf16x4 t0[4], t1[4], t2[4], t3[4];
#pragma unroll
    for (int i = 0; i < 4; i++) {
      t0[i] = ds_tr16(tl, i * 2048 + 0);
      t1[i] = ds_tr16(tl, i * 2048 + 128);
      t2[i] = ds_tr16(tl, i * 2048 + 1024);
      t3[i] = ds_tr16(tl, i * 2048 + 1152);
    }
    lgkm0();
    __builtin_amdgcn_sched_barrier(0);
    bf16x8 af[4][2];
#pragma unroll
    for (int i = 0; i < 4; i++) {
#pragma unroll
      for (int e = 0; e < 4; e++) {
        af[i][0][e] = t0[i][e]; af[i][0][e + 4] = t1[i][e];
        af[i][1][e] = t2[i][e]; af[i][1][e + 4] = t3[i][e];
      }
    }

    // Phase 3: feature MFMA, P loaded once per j2 directly from global (L1-resident)
    if (s == 0) {
#pragma unroll
      for (int j2 = 0; j2 < 4; j2++) {
        bf16x8 p0 = *(const bf16x8*)(P + (j2 * 16 + lm) * 64 + quad * 8);
        bf16x8 p1 = *(const bf16x8*)(P + (j2 * 16 + lm) * 64 + 32 + quad * 8);
#pragma unroll
        for (int i = 0; i < 4; i++) {
          f32x4 fa = {0.f, 0.f, 0.f, 0.f};
          fa = __builtin_amdgcn_mfma_f32_16x16x32_bf16(p0, af[i][0], fa, 0, 0, 0);
          fa = __builtin_amdgcn_mfma_f32_16x16x32_bf16(p1, af[i][1], fa, 0, 0, 0);
          bf16x4 o;
#pragma unroll
          for (int r = 0; r < 4; r++) {
            float v = fa[r] * 0.35355339f;
            o[r] = (bft)(fmaxf(v, 0.f) + 1e-6f);
          }
          const int n = nbs[i] + lm;
          if (n < SEQ)
            *(bf16x4*)(QF + ((size_t)(bb2s[i] * NH + h) * SEQ + n) * HD + j2 * 16 + quad * 4) = o;
        }
      }
    } else {
#pragma unroll
      for (int j2 = 0; j2 < 4; j2++) {
        bf16x8 p0 = *(const bf16x8*)(P + (j2 * 16 + lm) * 64 + quad * 8);
        bf16x8 p1 = *(const bf16x8*)(P + (j2 * 16 + lm) * 64 + 32 + quad * 8);
#pragma unroll
        for (int i = 0; i < 4; i++) {
          f32x4 fa = {0.f, 0.f, 0.f, 0.f};
          fa = __builtin_amdgcn_mfma_f32_16x16x32_bf16(af[i][0], p0, fa, 0, 0, 0);
          fa = __builtin_amdgcn_mfma_f32_16x16x32_bf16(af[i][1], p1, fa, 0, 0, 0);
          bf16x4 o;
#pragma unroll
          for (int r = 0; r < 4; r++) {
            float v = fa[r] * 0.35355339f;
            o[r] = (bft)(fmaxf(v, 0.f) + 1e-6f);
          }
          const int nq = nbs[i] + quad * 4;
          bft* rowp = KFT + ((size_t)(bb2s[i] * NH + h) * 64 + j2 * 16 + lm) * SEQP;
          if (nq + 3 <= 1024) {
            *(bf16x4*)(rowp + nq) = o;
          } else {
#pragma unroll
            for (int r = 0; r < 4; r++)
              if (nq + r <= 1024) rowp[nq + r] = o[r];
          }
        }
      }
    }
  } else {
    // v: direct from acc -> vT[e][n], b64 stores
#pragma unroll
    for (int i = 0; i < 4; i++) {
      const int tbase = m0 + wm + i * 16;
      const int bb2 = tbase / BSTR;
      const int nb = tbase - bb2 * BSTR;
      const int nq = nb + quad * 4;
#pragma unroll
      for (int j = 0; j < 4; j++) {
        bf16x4 o;
#pragma unroll
        for (int r = 0; r < 4; r++) o[r] = (bft)acc[i][j][r];
        bft* rowp = VT + ((size_t)(bb2 * NH + h) * 64 + j * 16 + lm) * SEQP;
        if (nq + 3 <= 1024) {
          *(bf16x4*)(rowp + nq) = o;
        } else {
#pragma unroll
          for (int r = 0; r < 4; r++)
            if (nq + r <= 1024) rowp[nq + r] = o[r];
        }
      }
    }
  }
}

// ---------------- K3: context partials via MFMA, LDS-free, no atomics ----------------
// grid (BHN, 4). Writes CTXP[y][bh] transposed [e][f] with f32x4; KSP[y][bh][f].
__global__ __launch_bounds__(256) void k_context(
    const bft* __restrict__ KFT, const bft* __restrict__ VT,
    float* __restrict__ CTXP, float* __restrict__ KSP) {
  const int tid = threadIdx.x;
  const int lane = tid & 63;
  const int lm = lane & 15;
  const int quad = lane >> 4;
  const int wid = tid >> 6;
  const int bh = blockIdx.x;
  const int y = blockIdx.y;
  const int c0 = (33 * y) / 4;
  const int c1 = (33 * (y + 1)) / 4;
  const bft* kb = KFT + (size_t)bh * 64 * SEQP + (size_t)(wid * 16 + lm) * SEQP + quad * 8;
  const bft* vb = VT + (size_t)bh * 64 * SEQP + (size_t)lm * SEQP + quad * 8;
  const int f0 = wid * 16;

  bf16x8 ones;
#pragma unroll
  for (int e = 0; e < 8; e++) ones[e] = (bft)1.0f;

  f32x4 acc[4] = {};
  f32x4 ak = {0.f, 0.f, 0.f, 0.f};

#pragma unroll 2
  for (int c = c0; c < c1; ++c) {
    const int t0 = c * 32;
    bf16x8 a = *(const bf16x8*)(kb + t0);
    ak = __builtin_amdgcn_mfma_f32_16x16x32_bf16(a, ones, ak, 0, 0, 0);
#pragma unroll
    for (int j = 0; j < 4; j++) {
      bf16x8 b = *(const bf16x8*)(vb + (size_t)j * 16 * SEQP + t0);
      acc[j] = __builtin_amdgcn_mfma_f32_16x16x32_bf16(a, b, acc[j], 0, 0, 0);
    }
  }

  // store transposed partial: CTXP[e][f], e = j*16+lm, f = f0+quad*4+r (f32x4 over r)
  float* cp = CTXP + ((size_t)(y * BHN) + bh) * 4096;
#pragma unroll
  for (int j = 0; j < 4; j++)
    *(f32x4*)(cp + (j * 16 + lm) * 64 + f0 + quad * 4) = acc[j];
  if (lm == 0)
    *(f32x4*)(KSP + ((size_t)(y * BHN) + bh) * 64 + f0 + quad * 4) = ak;
}

// ---------------- K3b: sum 4 partials, split into bf16 hi/lo (plain [e][f]) ----------------
__global__ __launch_bounds__(256) void k_ctxprep(
    const float* __restrict__ CTXP, const float* __restrict__ KSP,
    bft* __restrict__ CTH, bft* __restrict__ CTL,
    bft* __restrict__ KTH, bft* __restrict__ KTL) {
  const int bh = blockIdx.x;
  const int tid = threadIdx.x;
  const int e = tid >> 2;
  const int fc = tid & 3;
  f32x4 s[4] = {};
#pragma unroll
  for (int y = 0; y < 4; y++) {
    const float* src = CTXP + ((size_t)(y * BHN) + bh) * 4096 + e * 64 + fc * 16;
#pragma unroll
    for (int q = 0; q < 4; q++) {
      f32x4 v = *(const f32x4*)(src + q * 4);
      s[q][0] += v[0]; s[q][1] += v[1]; s[q][2] += v[2]; s[q][3] += v[3];
    }
  }
  bf16x8 h0, l0, h1, l1;
#pragma unroll
  for (int k = 0; k < 8; k++) {
    float v = s[k >> 2][k & 3];
    bft hi = (bft)v;
    h0[k] = hi; l0[k] = (bft)(v - (float)hi);
    float v2 = s[2 + (k >> 2)][k & 3];
    bft hi2 = (bft)v2;
    h1[k] = hi2; l1[k] = (bft)(v2 - (float)hi2);
  }
  bft* dh = CTH + (size_t)bh * 4096 + e * 64 + fc * 16;
  bft* dl = CTL + (size_t)bh * 4096 + e * 64 + fc * 16;
  *(bf16x8*)(dh) = h0;
  *(bf16x8*)(dh + 8) = h1;
  *(bf16x8*)(dl) = l0;
  *(bf16x8*)(dl + 8) = l1;
  if (tid < 64) {
    float v = 0.f;
#pragma unroll
    for (int y = 0; y < 4; y++) v += KSP[((size_t)(y * BHN) + bh) * 64 + tid];
    bft hi = (bft)v;
    KTH[bh * 64 + tid] = hi;
    KTL[bh * 64 + tid] = (bft)(v - (float)hi);
  }
}

// ---------------- K4: attn = (qf @ ctx) * Dinv via MFMA, LDS-free ----------------
__global__ __launch_bounds__(256) void k_qside(
    const bft* __restrict__ QF, const bft* __restrict__ CTH,
    const bft* __restrict__ CTL, const bft* __restrict__ KTH,
    const bft* __restrict__ KTL, bft* __restrict__ ATTN) {
  const int tid = threadIdx.x;
  const int lane = tid & 63;
  const int lm = lane & 15;
  const int quad = lane >> 4;
  const int wid = tid >> 6;
  const int bh = blockIdx.x;
  const int n0 = blockIdx.y * 128;
  const bft* qf = QF + ((size_t)bh * SEQ + n0) * HD;

  // ks fragments (A rows 0=hi,1=lo; others zero)
  bf16x8 kh0 = *(const bf16x8*)(KTH + bh * 64 + quad * 8);
  bf16x8 kh1 = *(const bf16x8*)(KTH + bh * 64 + 32 + quad * 8);
  bf16x8 kl0 = *(const bf16x8*)(KTL + bh * 64 + quad * 8);
  bf16x8 kl1 = *(const bf16x8*)(KTL + bh * 64 + 32 + quad * 8);
  bf16x8 zz = {};
  bf16x8 ad0 = (lm == 0) ? kh0 : (lm == 1) ? kl0 : zz;
  bf16x8 ad1 = (lm == 0) ? kh1 : (lm == 1) ? kl1 : zz;

  // ctx A fragments direct from global (plain [e][f] layout, L1/L2-resident)
  bf16x8 ah[4][2], al[4][2];
#pragma unroll
  for (int eb = 0; eb < 4; eb++)
#pragma unroll
    for (int kc = 0; kc < 2; kc++) {
      const size_t off = (size_t)bh * 4096 + (eb * 16 + lm) * 64 + kc * 32 + quad * 8;
      ah[eb][kc] = *(const bf16x8*)(CTH + off);
      al[eb][kc] = *(const bf16x8*)(CTL + off);
    }

  const int b = bh / NH;
  const int h = bh - b * NH;
#pragma unroll
  for (int tb2 = 0; tb2 < 2; tb2++) {
    const int tok0 = (wid * 2 + tb2) * 16;
    // clamp OOB rows to a valid address (results masked by store guard)
    const int rr = (n0 + tok0 + lm <= 1024) ? (tok0 + lm) : (1024 - n0);
    bf16x8 bq0 = *(const bf16x8*)(qf + (size_t)rr * 64 + quad * 8);
    bf16x8 bq1 = *(const bf16x8*)(qf + (size_t)rr * 64 + 32 + quad * 8);
    f32x4 dacc = {0.f, 0.f, 0.f, 0.f};
    dacc = __builtin_amdgcn_mfma_f32_16x16x32_bf16(ad0, bq0, dacc, 0, 0, 0);
    dacc = __builtin_amdgcn_mfma_f32_16x16x32_bf16(ad1, bq1, dacc, 0, 0, 0);
    const float den = __shfl(dacc[0] + dacc[1], lm);
    const float dinv = 1.0f / den;
    f32x4 fa[4] = {};
#pragma unroll
    for (int eb = 0; eb < 4; eb++) {
      fa[eb] = __builtin_amdgcn_mfma_f32_16x16x32_bf16(ah[eb][0], bq0, fa[eb], 0, 0, 0);
      fa[eb] = __builtin_amdgcn_mfma_f32_16x16x32_bf16(al[eb][0], bq0, fa[eb], 0, 0, 0);
      fa[eb] = __builtin_amdgcn_mfma_f32_16x16x32_bf16(ah[eb][1], bq1, fa[eb], 0, 0, 0);
      fa[eb] = __builtin_amdgcn_mfma_f32_16x16x32_bf16(al[eb][1], bq1, fa[eb], 0, 0, 0);
    }
    const int n = n0 + tok0 + lm;
    if (n < SEQ) {
      bft* dst = ATTN + ((size_t)(b * SEQ + n)) * DMODEL + h * 64;
#pragma unroll
      for (int eb = 0; eb < 4; eb++) {
        bf16x4 o;
#pragma unroll
        for (int r = 0; r < 4; r++) o[r] = (bft)(fa[eb][r] * dinv);
        *(bf16x4*)(dst + eb * 16 + quad * 4) = o;
      }
    }
  }
}

// ---------------- K5: out GEMM (M=32800, N=768, K=768) + bias, fp32 out ----------------
__global__ __launch_bounds__(256) void k_out_gemm(
    const bft* __restrict__ A, const bft* __restrict__ W,
    const float* __restrict__ BIAS, float* __restrict__ OUT) {
  __shared__ __align__(16) bft sA[128 * 64];
  __shared__ __align__(16) bft sB[128 * 64];
  const int tid = threadIdx.x;
  const int lane = tid & 63;
  const int lm = lane & 15;
  const int quad = lane >> 4;
  const int wid = tid >> 6;
  const int wm = (wid & 1) << 6;
  const int wn = (wid >> 1) << 6;
  const int lin = blockIdx.x;
  const int xcd = lin & 7;
  const int slot = lin >> 3;
  const int base = (xcd < 6) ? xcd * 193 : 6 * 193 + (xcd - 6) * 192;
  const int logical = base + slot;
  const int cb = logical % 6;
  const int rb = logical / 6;
  const int m0 = rb * 128;
  const int n0 = cb * 128;
  const int sw = lm & 7;
  const int o0 = (quad ^ sw) << 3;
  const int o1 = ((4 + quad) ^ sw) << 3;

  const bft* aptr[4];
  const bft* bptr[4];
#pragma unroll
  for (int it = 0; it < 4; it++) {
    int c = it * 256 + tid;
    int row = c >> 3;
    int col = ((c & 7) ^ (row & 7)) << 3;
    int ar = m0 + row;
    if (ar >= MROWS) ar = MROWS - 1;
    aptr[it] = A + (size_t)ar * DMODEL + col;
    bptr[it] = W + (size_t)(n0 + row) * DMODEL + col;
  }

  f32x4 acc[4][4] = {};

  for (int kt = 0; kt < DMODEL; kt += 64) {
#pragma unroll
    for (int it = 0; it < 4; it++) {
      int c = it * 256 + tid;
      gl_lds16(aptr[it], sA + c * 8);
      gl_lds16(bptr[it], sB + c * 8);
      aptr[it] += 64;
      bptr[it] += 64;
    }
    __syncthreads();
#pragma unroll
    for (int kk = 0; kk < 2; kk++) {
      const int off = kk ? o1 : o0;
      bf16x8 af[4], bb[4];
#pragma unroll
      for (int i = 0; i < 4; i++)
        af[i] = *(const bf16x8*)(sA + (wm + i * 16 + lm) * 64 + off);
#pragma unroll
      for (int j = 0; j < 4; j++)
        bb[j] = *(const bf16x8*)(sB + (wn + j * 16 + lm) * 64 + off);
      // swapped: D rows = g (from bb), cols = m (from af)
#pragma unroll
      for (int i = 0; i < 4; i++)
#pragma unroll
        for (int j = 0; j < 4; j++)
          acc[i][j] = __builtin_amdgcn_mfma_f32_16x16x32_bf16(bb[j], af[i], acc[i][j], 0, 0, 0);
    }
    __syncthreads();
  }

#pragma unroll
  for (int i = 0; i < 4; i++) {
    const int m = m0 + wm + i * 16 + lm;
    if (m < MROWS) {
#pragma unroll
      for (int j = 0; j < 4; j++) {
        const int g = n0 + wn + j * 16 + quad * 4;
        f32x4 bias = *(const f32x4*)(BIAS + g);
        f32x4 o;
#pragma unroll
        for (int r = 0; r < 4; r++) o[r] = acc[i][j][r] + bias[r];
        *(f32x4*)(OUT + (size_t)m * DMODEL + g) = o;
      }
    }
  }
}

extern "C" void kernel_launch(void* const* d_in, const int* in_sizes, int n_in,
                              void* d_out, int out_size, void* d_ws, size_t ws_size,
                              hipStream_t stream) {
  const float* x = (const float*)d_in[0];
  const float* wqkv = (const float*)d_in[1];
  const float* wout = (const float*)d_in[2];
  const float* bout = (const float*)d_in[3];
  const float* proj = (const float*)d_in[4];
  const float* fc = (const float*)d_in[5];
  const float* fs = (const float*)d_in[6];
  float* outp = (float*)d_out;

  char* ws = (char*)d_ws;
  const size_t xb_bytes = (size_t)MROWS * DMODEL * 2;        // 50,457,600
  const size_t qf_bytes = (size_t)BHN * SEQ * HD * 2;        // 50,380,800
  const size_t kt_bytes = (size_t)BHN * 64 * SEQP * 2;       // 51,904,512
  const size_t wqkvb_bytes = (size_t)3 * DMODEL * DMODEL * 2;
  const size_t woutb_bytes = (size_t)DMODEL * DMODEL * 2;
  const size_t projb_bytes = 8192;
  const size_t ctxp_bytes = (size_t)4 * BHN * 4096 * 4;      // 25,165,824
  const size_t ksp_bytes = (size_t)4 * BHN * 64 * 4;         // 393,216
  const size_t ctt_bytes = (size_t)BHN * 64 * 64 * 2;        // 3,145,728
  const size_t kst_bytes = (size_t)BHN * 64 * 2;             // 49,152
  const size_t ftab_bytes = (size_t)1040 * 32 * 4;           // 133,120

  bft* xb = (bft*)ws;                                  // X bf16; dead after k_qkv
  bft* qfb = (bft*)(ws + xb_bytes);
  bft* kft = (bft*)(ws + xb_bytes + qf_bytes);         // dead after k_context -> attn
  bft* vt = (bft*)(ws + xb_bytes + qf_bytes + kt_bytes);
  bft* wqkvb = (bft*)(ws + xb_bytes + qf_bytes + 2 * kt_bytes);
  bft* woutb = (bft*)(ws + xb_bytes + qf_bytes + 2 * kt_bytes + wqkvb_bytes);
  bft* projb = (bft*)(ws + xb_bytes + qf_bytes + 2 * kt_bytes + wqkvb_bytes + woutb_bytes);
  float* fcp = (float*)(ws + xb_bytes + qf_bytes + 2 * kt_bytes + wqkvb_bytes + woutb_bytes + projb_bytes);
  float* fsp = (float*)(ws + xb_bytes + qf_bytes + 2 * kt_bytes + wqkvb_bytes + woutb_bytes + projb_bytes + ftab_bytes);

  // aliases into xb region (live only after k_qkv; 32.0 MB < 50.4 MB)
  float* ctxp = (float*)ws;
  float* ksp = (float*)(ws + ctxp_bytes);
  bft* cth = (bft*)(ws + ctxp_bytes + ksp_bytes);
  bft* ctl = (bft*)(ws + ctxp_bytes + ksp_bytes + ctt_bytes);
  bft* kth = (bft*)(ws + ctxp_bytes + ksp_bytes + 2 * ctt_bytes);
  bft* ktl = (bft*)(ws + ctxp_bytes + ksp_bytes + 2 * ctt_bytes + kst_bytes);
  bft* attn = kft;  // alias kfT region (dead after k_context)

  dim3 blk(256);
  k_prep<<<dim3((S5P + 255) / 256), blk, 0, stream>>>(
      x, wqkv, wout, proj, fc, fs, xb, wqkvb, woutb, projb, kft, vt, fcp, fsp);
  k_qkv_gemm<<<dim3(4680), blk, 0, stream>>>(xb, wqkvb, projb, fcp, fsp, qfb, kft, vt);
  k_context<<<dim3(BHN, 4), blk, 0, stream>>>(kft, vt, ctxp, ksp);
  k_ctxprep<<<dim3(BHN), blk, 0, stream>>>(ctxp, ksp, cth, ctl, kth, ktl);
  k_qside<<<dim3(BHN, 9), blk, 0, stream>>>(qfb, cth, ctl, kth, ktl, attn);
  k_out_gemm<<<dim3(1542), blk, 0, stream>>>(attn, woutb, bout, outp);
  (void)in_sizes; (void)n_in; (void)out_size; (void)ws_size;
}